// Round 11
// baseline (719.539 us; speedup 1.0000x reference)
//
#include <hip/hip_runtime.h>

#define B_   4
#define S_   2048
#define HID  1024
#define NH   16
#define CH   64
#define M_   (B_ * S_)      // 8192
#define N3   (3 * HID)      // 3072
#define LDT2 72             // padded LDS row stride (144 B = 9*16B: aligned b128, ~2-way bank alias = free)

typedef __attribute__((ext_vector_type(4))) float f32x4;
typedef __attribute__((ext_vector_type(8))) unsigned short u16x8;
typedef __attribute__((ext_vector_type(4))) unsigned short u16x4;

__device__ __forceinline__ unsigned short f2bf(float x) {
    unsigned u = __builtin_bit_cast(unsigned, x);
    u += 0x7fffu + ((u >> 16) & 1u);
    return (unsigned short)(u >> 16);
}
__device__ __forceinline__ float bf2f(unsigned short h) {
    unsigned u = ((unsigned)h) << 16;
    return __builtin_bit_cast(float, u);
}
__device__ __forceinline__ f32x4 mfma16(u16x8 a, u16x8 b, f32x4 c) {
    asm("v_mfma_f32_16x16x32_bf16 %0, %1, %2, %0" : "+v"(c) : "v"(a), "v"(b));
    return c;
}

// ---------------- kernel 1: elementwise hi/lo split (encodings -> A_hi/A_lo bf16) ------
__global__ __launch_bounds__(256) void k_split(const float* __restrict__ x,
                                               unsigned short* __restrict__ hi,
                                               unsigned short* __restrict__ lo,
                                               int n8) {
    int idx = blockIdx.x * 256 + threadIdx.x;
    if (idx >= n8) return;
    const f32x4* px = (const f32x4*)x + (size_t)idx * 2;
    f32x4 a = px[0], b = px[1];
    u16x8 h, l;
#pragma unroll
    for (int i = 0; i < 8; i++) {
        float xv = (i < 4) ? a[i] : b[i - 4];
        unsigned short hb = f2bf(xv);
        h[i] = hb;
        l[i] = f2bf(xv - bf2f(hb));
    }
    *(u16x8*)(hi + (size_t)idx * 8) = h;
    *(u16x8*)(lo + (size_t)idx * 8) = l;
}

// ---------------- kernel 2: transpose + hi/lo split (W[k][n] -> WT[n][k]) --------------
__global__ __launch_bounds__(256) void k_tsplit(const float* __restrict__ W,
                                                unsigned short* __restrict__ WTh,
                                                unsigned short* __restrict__ WTl) {
    __shared__ float tile[32][33];
    int n0 = blockIdx.x * 32, k0 = blockIdx.y * 32;
    int tid = threadIdx.x;
    int r = tid >> 3, c0 = (tid & 7) * 4;
    f32x4 v = *(const f32x4*)(W + (size_t)(k0 + r) * N3 + n0 + c0);
#pragma unroll
    for (int i = 0; i < 4; i++) tile[r][c0 + i] = v[i];
    __syncthreads();
    u16x4 h, l;
#pragma unroll
    for (int i = 0; i < 4; i++) {
        float xv = tile[c0 + i][r];
        unsigned short hb = f2bf(xv);
        h[i] = hb;
        l[i] = f2bf(xv - bf2f(hb));
    }
    size_t o = (size_t)(n0 + r) * HID + k0 + c0;
    *(u16x4*)(WTh + o) = h;
    *(u16x4*)(WTl + o) = l;
}

// ---------------- kernel 3: QKV GEMM (3-term hi/lo bf16), BK=64, reg-prefetch ----------
__global__ __launch_bounds__(256, 2) void k_gemm(
    const unsigned short* __restrict__ Ah, const unsigned short* __restrict__ Al,
    const unsigned short* __restrict__ Bh, const unsigned short* __restrict__ Bl,
    const float* __restrict__ bias,
    unsigned short* __restrict__ Qh, unsigned short* __restrict__ Ql,
    unsigned short* __restrict__ Kh, unsigned short* __restrict__ Kl,
    unsigned short* __restrict__ Vt) {
    __shared__ __attribute__((aligned(16))) unsigned short sAh[128 * LDT2];
    __shared__ __attribute__((aligned(16))) unsigned short sAl[128 * LDT2];
    __shared__ __attribute__((aligned(16))) unsigned short sBh[128 * LDT2];
    __shared__ __attribute__((aligned(16))) unsigned short sBl[128 * LDT2];
    int tid = threadIdx.x;
    int m0 = blockIdx.y * 128, n0 = blockIdx.x * 128;
    int r = tid >> 1, kh2 = (tid & 1) * 32;
    int lane = tid & 63, w = tid >> 6;
    int wm = (w >> 1) * 64, wn = (w & 1) * 64;
    int l15 = lane & 15, l4 = lane >> 4;
    f32x4 acc[4][4] = {};
    size_t gA = (size_t)(m0 + r) * HID + kh2;
    size_t gB = (size_t)(n0 + r) * HID + kh2;

    u16x8 pf[4][4];
#pragma unroll
    for (int j = 0; j < 4; j++) {
        pf[0][j] = *(const u16x8*)(Ah + gA + j * 8);
        pf[1][j] = *(const u16x8*)(Al + gA + j * 8);
        pf[2][j] = *(const u16x8*)(Bh + gB + j * 8);
        pf[3][j] = *(const u16x8*)(Bl + gB + j * 8);
    }
#pragma unroll
    for (int j = 0; j < 4; j++) {
        *(u16x8*)&sAh[r * LDT2 + kh2 + j * 8] = pf[0][j];
        *(u16x8*)&sAl[r * LDT2 + kh2 + j * 8] = pf[1][j];
        *(u16x8*)&sBh[r * LDT2 + kh2 + j * 8] = pf[2][j];
        *(u16x8*)&sBl[r * LDT2 + kh2 + j * 8] = pf[3][j];
    }

    for (int k0 = 0; k0 < HID; k0 += 64) {
        __syncthreads();                       // staged tile visible to all waves
        bool more = (k0 + 64 < HID);
        if (more) {                            // prefetch next tile into registers
#pragma unroll
            for (int j = 0; j < 4; j++) {
                pf[0][j] = *(const u16x8*)(Ah + gA + k0 + 64 + j * 8);
                pf[1][j] = *(const u16x8*)(Al + gA + k0 + 64 + j * 8);
                pf[2][j] = *(const u16x8*)(Bh + gB + k0 + 64 + j * 8);
                pf[3][j] = *(const u16x8*)(Bl + gB + k0 + 64 + j * 8);
            }
        }
#pragma unroll
        for (int ks = 0; ks < 64; ks += 32) {
            u16x8 a0[4], a1[4], b0[4], b1[4];
#pragma unroll
            for (int i = 0; i < 4; i++) {
                int off = ks + l4 * 8;
                int row = wm + i * 16 + l15;
                a0[i] = *(const u16x8*)&sAh[row * LDT2 + off];
                a1[i] = *(const u16x8*)&sAl[row * LDT2 + off];
                int rowb = wn + i * 16 + l15;
                b0[i] = *(const u16x8*)&sBh[rowb * LDT2 + off];
                b1[i] = *(const u16x8*)&sBl[rowb * LDT2 + off];
            }
#pragma unroll
            for (int mt = 0; mt < 4; mt++)
#pragma unroll
                for (int nt = 0; nt < 4; nt++) {
                    acc[mt][nt] = mfma16(a0[mt], b0[nt], acc[mt][nt]);
                    acc[mt][nt] = mfma16(a0[mt], b1[nt], acc[mt][nt]);
                    acc[mt][nt] = mfma16(a1[mt], b0[nt], acc[mt][nt]);
                }
        }
        __syncthreads();                       // all waves done reading this tile
        if (more) {
#pragma unroll
            for (int j = 0; j < 4; j++) {
                *(u16x8*)&sAh[r * LDT2 + kh2 + j * 8] = pf[0][j];
                *(u16x8*)&sAl[r * LDT2 + kh2 + j * 8] = pf[1][j];
                *(u16x8*)&sBh[r * LDT2 + kh2 + j * 8] = pf[2][j];
                *(u16x8*)&sBl[r * LDT2 + kh2 + j * 8] = pf[3][j];
            }
        }
    }

    // epilogue: +bias, split by destination, hi/lo-convert, scatter per-head
#pragma unroll
    for (int mt = 0; mt < 4; mt++)
#pragma unroll
        for (int nt = 0; nt < 4; nt++) {
            int n = n0 + wn + nt * 16 + l15;
            float bv = bias[n];
            int which = n >> 10, hid = n & 1023;
            int h = hid >> 6, c = hid & 63;
            int mbase = m0 + wm + mt * 16 + l4 * 4;
            int b = mbase >> 11, sbase = mbase & 2047;
            int bh = b * NH + h;
            if (which == 2) {                  // V -> transposed bf16 [bh][c][s]
                u16x4 pv;
#pragma unroll
                for (int jj = 0; jj < 4; jj++) pv[jj] = f2bf(acc[mt][nt][jj] + bv);
                *(u16x4*)(Vt + ((size_t)bh * CH + c) * S_ + sbase) = pv;
            } else {
                unsigned short* __restrict__ dh = (which == 0) ? Qh : Kh;
                unsigned short* __restrict__ dl = (which == 0) ? Ql : Kl;
                float sc = (which == 0) ? 0.125f : 1.0f;
#pragma unroll
                for (int jj = 0; jj < 4; jj++) {
                    float val = (acc[mt][nt][jj] + bv) * sc;
                    unsigned short hb = f2bf(val);
                    size_t so = ((size_t)bh * S_ + sbase + jj) * CH + c;
                    dh[so] = hb;
                    dl[so] = f2bf(val - bf2f(hb));
                }
            }
        }
}

// ---------------- kernel 4: causal flash attention, T14 software-pipelined staging -----
// Loop: {sync; QKT; sync; ISSUE kt+1 loads -> regs; softmax; PV; sync; regs -> LDS}.
// Staging latency (the round-9 300us dominator: MFMA+VALU only 26% busy) now overlaps
// the ~2000cy softmax+PV phase instead of sitting exposed between two barriers.
// Cost: +48 held VGPRs (~180 total, tier 129-256 -> 8 waves/CU). (256,2): cap 256, no
// spills (rounds 3/6: cap 170 -> VGPR=84 + 190MB scratch; verify WRITE_SIZE stays 41MB).
__global__ __launch_bounds__(256, 2) void k_attn(const unsigned short* __restrict__ Qh,
                                                 const unsigned short* __restrict__ Ql,
                                                 const unsigned short* __restrict__ Kh,
                                                 const unsigned short* __restrict__ Kl,
                                                 const unsigned short* __restrict__ Vt,
                                                 float* __restrict__ out) {
    __shared__ __attribute__((aligned(16))) unsigned short sKbuf[2 * 128 * 64]; // Kh|Kl, reused as P
    __shared__ __attribute__((aligned(16))) unsigned short sVT[64 * 128];
    char* const sKhB = (char*)sKbuf;            // 16 KB
    char* const sKlB = (char*)sKbuf + 16384;    // 16 KB
    int tid = threadIdx.x, lane = tid & 63, w = tid >> 6;
    int l15 = lane & 15, l4 = lane >> 4;
    char* const sPB = (char*)sKbuf + w * 8192;  // wave-private 8 KB P buffer (overlays K)
    int qt = gridDim.x - 1 - blockIdx.x;        // heavy blocks first
    int bh = blockIdx.y;
    int b = bh >> 4, h = bh & 15;
    size_t head_off = (size_t)bh * S_ * CH;
    const unsigned short* Qhp = Qh + head_off;
    const unsigned short* Qlp = Ql + head_off;
    const unsigned short* Khp = Kh + head_off;
    const unsigned short* Klp = Kl + head_off;
    const unsigned short* Vtp = Vt + (size_t)bh * CH * S_;

    // loop-invariant staging geometry (per thread): K rows 128B swz=(r&7)<<4,
    // V^T rows 256B swz=(c&15)<<4; coalesced u16x8 slots
    int kld[4], vld[4];
    size_t kg[4], vg[4];
#pragma unroll
    for (int j = 0; j < 4; j++) {
        int idx = tid + j * 256;
        int rr = idx >> 3, sl = idx & 7;
        kld[j] = rr * 128 + ((sl * 16) ^ ((rr & 7) << 4));
        kg[j]  = (size_t)rr * CH + sl * 8;
        int cc = idx >> 4, sv = idx & 15;
        vld[j] = cc * 256 + ((sv * 16) ^ ((cc & 15) << 4));
        vg[j]  = (size_t)cc * S_ + sv * 8;
    }

    // Q fragments (already scaled by 1/8 and hi/lo split)
    u16x8 qh[2][2], ql[2][2];
#pragma unroll
    for (int m = 0; m < 2; m++)
#pragma unroll
        for (int cc = 0; cc < 2; cc++) {
            size_t o = (size_t)(qt * 128 + w * 32 + m * 16 + l15) * CH + cc * 32 + l4 * 8;
            qh[m][cc] = *(const u16x8*)(Qhp + o);
            ql[m][cc] = *(const u16x8*)(Qlp + o);
        }

    f32x4 ctx[2][4] = {};
    float mrun[2][4], lrun[2][4];
#pragma unroll
    for (int m = 0; m < 2; m++)
#pragma unroll
        for (int j = 0; j < 4; j++) { mrun[m][j] = -1e30f; lrun[m][j] = 0.f; }

    // prologue: stage tile 0
#pragma unroll
    for (int j = 0; j < 4; j++) {
        u16x8 a = *(const u16x8*)(Khp + kg[j]);
        u16x8 c = *(const u16x8*)(Klp + kg[j]);
        u16x8 v = *(const u16x8*)(Vtp + vg[j]);
        *(u16x8*)(sKhB + kld[j]) = a;
        *(u16x8*)(sKlB + kld[j]) = c;
        *(u16x8*)((char*)sVT + vld[j]) = v;
    }

    for (int kt = 0; kt <= qt; kt++) {
        __syncthreads();   // tile kt visible (prologue or prev iter's reg->LDS writes)

        // scores: S = (Q/8) K^T, 3-term bf16
        f32x4 sa[2][8];
#pragma unroll
        for (int m = 0; m < 2; m++)
#pragma unroll
            for (int nt = 0; nt < 8; nt++) sa[m][nt] = f32x4{0.f, 0.f, 0.f, 0.f};
        __builtin_amdgcn_s_setprio(1);
#pragma unroll
        for (int nt = 0; nt < 8; nt++) {
            int rowb = nt * 16 + l15;
            int swb = (rowb & 7) << 4;
            u16x8 kbh[2], kbl[2];
#pragma unroll
            for (int cc = 0; cc < 2; cc++) {
                int off = (cc * 64 + l4 * 16) ^ swb;
                kbh[cc] = *(const u16x8*)(sKhB + rowb * 128 + off);
                kbl[cc] = *(const u16x8*)(sKlB + rowb * 128 + off);
            }
#pragma unroll
            for (int m = 0; m < 2; m++)
#pragma unroll
                for (int cc = 0; cc < 2; cc++) {
                    sa[m][nt] = mfma16(qh[m][cc], kbh[cc], sa[m][nt]);
                    sa[m][nt] = mfma16(qh[m][cc], kbl[cc], sa[m][nt]);
                    sa[m][nt] = mfma16(ql[m][cc], kbh[cc], sa[m][nt]);
                }
        }
        __builtin_amdgcn_s_setprio(0);
        if (kt == qt) {  // causal mask inside diagonal tile
#pragma unroll
            for (int m = 0; m < 2; m++)
#pragma unroll
                for (int nt = 0; nt < 8; nt++) {
                    int t = nt * 16 + l15;
#pragma unroll
                    for (int jj = 0; jj < 4; jj++) {
                        int f = w * 32 + m * 16 + l4 * 4 + jj;
                        if (t > f) sa[m][nt][jj] = -10000.0f;
                    }
                }
        }
        __syncthreads();   // all waves done reading K; K region becomes P region

        // T14: issue next tile's global loads NOW -> they fly during softmax+PV
        bool more = (kt < qt);
        u16x8 pfh[4], pfl[4], pfv[4];
        if (more) {
            size_t ko = (size_t)(kt + 1) * 128 * CH;
            size_t vo = (size_t)(kt + 1) * 128;
#pragma unroll
            for (int j = 0; j < 4; j++) {
                pfh[j] = *(const u16x8*)(Khp + ko + kg[j]);
                pfl[j] = *(const u16x8*)(Klp + ko + kg[j]);
                pfv[j] = *(const u16x8*)(Vtp + vo + vg[j]);
            }
        }

        // online softmax (wave-parallel 16-lane-group reduce) + P -> swizzled LDS bf16
        // P[row][col] at byte row*256 + ((col*2) ^ ((row&15)<<4)): conflict-free for
        // both the 2B scatter and the b128 reads.
#pragma unroll
        for (int m = 0; m < 2; m++)
#pragma unroll
            for (int jj = 0; jj < 4; jj++) {
                float rx = sa[m][0][jj];
#pragma unroll
                for (int nt = 1; nt < 8; nt++) rx = fmaxf(rx, sa[m][nt][jj]);
                rx = fmaxf(rx, __shfl_xor(rx, 1));
                rx = fmaxf(rx, __shfl_xor(rx, 2));
                rx = fmaxf(rx, __shfl_xor(rx, 4));
                rx = fmaxf(rx, __shfl_xor(rx, 8));
                float mnew = fmaxf(mrun[m][jj], rx);
                float sc = __expf(mrun[m][jj] - mnew);
                mrun[m][jj] = mnew;
                float ps = 0.f;
                int fm = m * 16 + l4 * 4 + jj;
                int swp = (fm & 15) << 4;
#pragma unroll
                for (int nt = 0; nt < 8; nt++) {
                    float p = __expf(sa[m][nt][jj] - mnew);
                    ps += p;
                    int bo = ((nt * 16 + l15) * 2) ^ swp;
                    *(unsigned short*)(sPB + fm * 256 + bo) = f2bf(p);
                }
                lrun[m][jj] = lrun[m][jj] * sc + ps;
#pragma unroll
                for (int nc = 0; nc < 4; nc++) ctx[m][nc][jj] *= sc;
            }
        // PV: ctx += P @ V (P wave-private; compiler inserts lgkm waits)
        __builtin_amdgcn_s_setprio(1);
#pragma unroll
        for (int tk = 0; tk < 4; tk++) {
            u16x8 pa[2];
#pragma unroll
            for (int m = 0; m < 2; m++) {
                int row = m * 16 + l15;
                int off = (tk * 64 + l4 * 16) ^ ((row & 15) << 4);
                pa[m] = *(const u16x8*)(sPB + row * 256 + off);
            }
#pragma unroll
            for (int nc = 0; nc < 4; nc++) {
                int rowv = nc * 16 + l15;
                int off = (tk * 64 + l4 * 16) ^ ((rowv & 15) << 4);
                u16x8 vb = *(const u16x8*)((char*)sVT + rowv * 256 + off);
#pragma unroll
                for (int m = 0; m < 2; m++) ctx[m][nc] = mfma16(pa[m], vb, ctx[m][nc]);
            }
        }
        __builtin_amdgcn_s_setprio(0);

        __syncthreads();   // all waves done reading P (K-overlay) and V
        if (more) {        // write prefetched tile kt+1 (loads have had softmax+PV to land)
#pragma unroll
            for (int j = 0; j < 4; j++) {
                *(u16x8*)(sKhB + kld[j]) = pfh[j];
                *(u16x8*)(sKlB + kld[j]) = pfl[j];
                *(u16x8*)((char*)sVT + vld[j]) = pfv[j];
            }
        }
    }
    // finalize: divide by row sum, store
#pragma unroll
    for (int m = 0; m < 2; m++)
#pragma unroll
        for (int jj = 0; jj < 4; jj++) {
            float ls = lrun[m][jj];
            ls += __shfl_xor(ls, 1);
            ls += __shfl_xor(ls, 2);
            ls += __shfl_xor(ls, 4);
            ls += __shfl_xor(ls, 8);
            float inv = 1.0f / ls;
            int f = qt * 128 + w * 32 + m * 16 + l4 * 4 + jj;
#pragma unroll
            for (int nc = 0; nc < 4; nc++) {
                int c = nc * 16 + l15;
                out[((size_t)(b * S_ + f)) * HID + h * CH + c] = ctx[m][nc][jj] * inv;
            }
        }
}

extern "C" void kernel_launch(void* const* d_in, const int* in_sizes, int n_in,
                              void* d_out, int out_size, void* d_ws, size_t ws_size,
                              hipStream_t stream) {
    const float* enc  = (const float*)d_in[0];
    const float* W    = (const float*)d_in[1];
    const float* bias = (const float*)d_in[2];
    float* out = (float*)d_out;

    unsigned short* A_hi = (unsigned short*)d_ws;
    unsigned short* A_lo = A_hi + (size_t)M_ * HID;
    unsigned short* WTh  = A_lo + (size_t)M_ * HID;
    unsigned short* WTl  = WTh + (size_t)N3 * HID;
    unsigned short* Qh   = WTl + (size_t)N3 * HID;
    unsigned short* Ql   = Qh + (size_t)M_ * HID;
    unsigned short* Kh   = Ql + (size_t)M_ * HID;
    unsigned short* Kl   = Kh + (size_t)M_ * HID;
    unsigned short* Vt   = Kl + (size_t)M_ * HID;

    int n8 = (M_ * HID) / 8;
    k_split<<<dim3(n8 / 256), 256, 0, stream>>>(enc, A_hi, A_lo, n8);
    k_tsplit<<<dim3(N3 / 32, HID / 32), 256, 0, stream>>>(W, WTh, WTl);
    k_gemm<<<dim3(N3 / 128, M_ / 128), 256, 0, stream>>>(A_hi, A_lo, WTh, WTl, bias,
                                                         Qh, Ql, Kh, Kl, Vt);
    k_attn<<<dim3(S_ / 128, B_ * NH), 256, 0, stream>>>(Qh, Ql, Kh, Kl, Vt, out);
}

// Round 12
// 477.955 us; speedup vs baseline: 1.5055x; 1.5055x over previous
//
#include <hip/hip_runtime.h>

#define B_   4
#define S_   2048
#define HID  1024
#define NH   16
#define CH   64
#define M_   (B_ * S_)      // 8192
#define N3   (3 * HID)      // 3072
#define LDT2 72             // padded LDS row stride (144 B = 9*16B: aligned b128, ~2-way bank alias = free)

typedef __attribute__((ext_vector_type(4))) float f32x4;
typedef __attribute__((ext_vector_type(8))) unsigned short u16x8;
typedef __attribute__((ext_vector_type(4))) unsigned short u16x4;

__device__ __forceinline__ unsigned short f2bf(float x) {
    unsigned u = __builtin_bit_cast(unsigned, x);
    u += 0x7fffu + ((u >> 16) & 1u);
    return (unsigned short)(u >> 16);
}
__device__ __forceinline__ float bf2f(unsigned short h) {
    unsigned u = ((unsigned)h) << 16;
    return __builtin_bit_cast(float, u);
}
// D = A*B + C. Output: M-row = (lane>>4)*4+reg, N-col = lane&15.
// A-frag: M-row = lane&15, k = (lane>>4)*8. B-frag: N-row = lane&15, k = (lane>>4)*8.
__device__ __forceinline__ f32x4 mfma16(u16x8 a, u16x8 b, f32x4 c) {
    asm("v_mfma_f32_16x16x32_bf16 %0, %1, %2, %0" : "+v"(c) : "v"(a), "v"(b));
    return c;
}

// ---------------- kernel 1: elementwise hi/lo split (encodings -> A_hi/A_lo bf16) ------
__global__ __launch_bounds__(256) void k_split(const float* __restrict__ x,
                                               unsigned short* __restrict__ hi,
                                               unsigned short* __restrict__ lo,
                                               int n8) {
    int idx = blockIdx.x * 256 + threadIdx.x;
    if (idx >= n8) return;
    const f32x4* px = (const f32x4*)x + (size_t)idx * 2;
    f32x4 a = px[0], b = px[1];
    u16x8 h, l;
#pragma unroll
    for (int i = 0; i < 8; i++) {
        float xv = (i < 4) ? a[i] : b[i - 4];
        unsigned short hb = f2bf(xv);
        h[i] = hb;
        l[i] = f2bf(xv - bf2f(hb));
    }
    *(u16x8*)(hi + (size_t)idx * 8) = h;
    *(u16x8*)(lo + (size_t)idx * 8) = l;
}

// ---------------- kernel 2: transpose + hi/lo split (W[k][n] -> WT[n][k]) --------------
__global__ __launch_bounds__(256) void k_tsplit(const float* __restrict__ W,
                                                unsigned short* __restrict__ WTh,
                                                unsigned short* __restrict__ WTl) {
    __shared__ float tile[32][33];
    int n0 = blockIdx.x * 32, k0 = blockIdx.y * 32;
    int tid = threadIdx.x;
    int r = tid >> 3, c0 = (tid & 7) * 4;
    f32x4 v = *(const f32x4*)(W + (size_t)(k0 + r) * N3 + n0 + c0);
#pragma unroll
    for (int i = 0; i < 4; i++) tile[r][c0 + i] = v[i];
    __syncthreads();
    u16x4 h, l;
#pragma unroll
    for (int i = 0; i < 4; i++) {
        float xv = tile[c0 + i][r];
        unsigned short hb = f2bf(xv);
        h[i] = hb;
        l[i] = f2bf(xv - bf2f(hb));
    }
    size_t o = (size_t)(n0 + r) * HID + k0 + c0;
    *(u16x4*)(WTh + o) = h;
    *(u16x4*)(WTl + o) = l;
}

// ---------------- kernel 3: QKV GEMM (3-term hi/lo bf16), BK=64, reg-prefetch ----------
__global__ __launch_bounds__(256, 2) void k_gemm(
    const unsigned short* __restrict__ Ah, const unsigned short* __restrict__ Al,
    const unsigned short* __restrict__ Bh, const unsigned short* __restrict__ Bl,
    const float* __restrict__ bias,
    unsigned short* __restrict__ Qh, unsigned short* __restrict__ Ql,
    unsigned short* __restrict__ Kh, unsigned short* __restrict__ Kl,
    unsigned short* __restrict__ Vt) {
    __shared__ __attribute__((aligned(16))) unsigned short sAh[128 * LDT2];
    __shared__ __attribute__((aligned(16))) unsigned short sAl[128 * LDT2];
    __shared__ __attribute__((aligned(16))) unsigned short sBh[128 * LDT2];
    __shared__ __attribute__((aligned(16))) unsigned short sBl[128 * LDT2];
    int tid = threadIdx.x;
    int m0 = blockIdx.y * 128, n0 = blockIdx.x * 128;
    int r = tid >> 1, kh2 = (tid & 1) * 32;
    int lane = tid & 63, w = tid >> 6;
    int wm = (w >> 1) * 64, wn = (w & 1) * 64;
    int l15 = lane & 15, l4 = lane >> 4;
    f32x4 acc[4][4] = {};
    size_t gA = (size_t)(m0 + r) * HID + kh2;
    size_t gB = (size_t)(n0 + r) * HID + kh2;

    u16x8 pf[4][4];
#pragma unroll
    for (int j = 0; j < 4; j++) {
        pf[0][j] = *(const u16x8*)(Ah + gA + j * 8);
        pf[1][j] = *(const u16x8*)(Al + gA + j * 8);
        pf[2][j] = *(const u16x8*)(Bh + gB + j * 8);
        pf[3][j] = *(const u16x8*)(Bl + gB + j * 8);
    }
#pragma unroll
    for (int j = 0; j < 4; j++) {
        *(u16x8*)&sAh[r * LDT2 + kh2 + j * 8] = pf[0][j];
        *(u16x8*)&sAl[r * LDT2 + kh2 + j * 8] = pf[1][j];
        *(u16x8*)&sBh[r * LDT2 + kh2 + j * 8] = pf[2][j];
        *(u16x8*)&sBl[r * LDT2 + kh2 + j * 8] = pf[3][j];
    }

    for (int k0 = 0; k0 < HID; k0 += 64) {
        __syncthreads();                       // staged tile visible to all waves
        bool more = (k0 + 64 < HID);
        if (more) {                            // prefetch next tile into registers
#pragma unroll
            for (int j = 0; j < 4; j++) {
                pf[0][j] = *(const u16x8*)(Ah + gA + k0 + 64 + j * 8);
                pf[1][j] = *(const u16x8*)(Al + gA + k0 + 64 + j * 8);
                pf[2][j] = *(const u16x8*)(Bh + gB + k0 + 64 + j * 8);
                pf[3][j] = *(const u16x8*)(Bl + gB + k0 + 64 + j * 8);
            }
        }
#pragma unroll
        for (int ks = 0; ks < 64; ks += 32) {
            u16x8 a0[4], a1[4], b0[4], b1[4];
#pragma unroll
            for (int i = 0; i < 4; i++) {
                int off = ks + l4 * 8;
                int row = wm + i * 16 + l15;
                a0[i] = *(const u16x8*)&sAh[row * LDT2 + off];
                a1[i] = *(const u16x8*)&sAl[row * LDT2 + off];
                int rowb = wn + i * 16 + l15;
                b0[i] = *(const u16x8*)&sBh[rowb * LDT2 + off];
                b1[i] = *(const u16x8*)&sBl[rowb * LDT2 + off];
            }
#pragma unroll
            for (int mt = 0; mt < 4; mt++)
#pragma unroll
                for (int nt = 0; nt < 4; nt++) {
                    acc[mt][nt] = mfma16(a0[mt], b0[nt], acc[mt][nt]);
                    acc[mt][nt] = mfma16(a0[mt], b1[nt], acc[mt][nt]);
                    acc[mt][nt] = mfma16(a1[mt], b0[nt], acc[mt][nt]);
                }
        }
        __syncthreads();                       // all waves done reading this tile
        if (more) {
#pragma unroll
            for (int j = 0; j < 4; j++) {
                *(u16x8*)&sAh[r * LDT2 + kh2 + j * 8] = pf[0][j];
                *(u16x8*)&sAl[r * LDT2 + kh2 + j * 8] = pf[1][j];
                *(u16x8*)&sBh[r * LDT2 + kh2 + j * 8] = pf[2][j];
                *(u16x8*)&sBl[r * LDT2 + kh2 + j * 8] = pf[3][j];
            }
        }
    }

    // epilogue: +bias, split by destination, hi/lo-convert, scatter per-head
#pragma unroll
    for (int mt = 0; mt < 4; mt++)
#pragma unroll
        for (int nt = 0; nt < 4; nt++) {
            int n = n0 + wn + nt * 16 + l15;
            float bv = bias[n];
            int which = n >> 10, hid = n & 1023;
            int h = hid >> 6, c = hid & 63;
            int mbase = m0 + wm + mt * 16 + l4 * 4;
            int b = mbase >> 11, sbase = mbase & 2047;
            int bh = b * NH + h;
            if (which == 2) {                  // V -> transposed bf16 [bh][c][s]
                u16x4 pv;
#pragma unroll
                for (int jj = 0; jj < 4; jj++) pv[jj] = f2bf(acc[mt][nt][jj] + bv);
                *(u16x4*)(Vt + ((size_t)bh * CH + c) * S_ + sbase) = pv;
            } else {
                unsigned short* __restrict__ dh = (which == 0) ? Qh : Kh;
                unsigned short* __restrict__ dl = (which == 0) ? Ql : Kl;
                float sc = (which == 0) ? 0.125f : 1.0f;
#pragma unroll
                for (int jj = 0; jj < 4; jj++) {
                    float val = (acc[mt][nt][jj] + bv) * sc;
                    unsigned short hb = f2bf(val);
                    size_t so = ((size_t)bh * S_ + sbase + jj) * CH + c;
                    dh[so] = hb;
                    dl[so] = f2bf(val - bf2f(hb));
                }
            }
        }
}

// ---------------- kernel 4: causal flash attention, SWAPPED QK^T in-register softmax ---
// sa = mfma(K, Q): output N(=Q-row f) <-> l15, M(=t) <-> l4*4+jj. Each lane owns whole
// Q rows -> row max/sum = 31 in-reg fmax + 2 shfl per nf (was 4 shfl x 8 combos = 32).
// P stored [f][t] via packed u16x4 (16 stores vs 64 scalar); PV swapped too:
// ctx^T = mfma(V^T, P) -> A = sVT rows (c), B = P rows (f). lrun fully lane-local,
// final-division shfl block deleted; out stores become f32x4.
// T14 reg-prefetch REVERTED (round 11: compiler pins 128 VGPR, spills -> +236MB scratch).
__global__ __launch_bounds__(256, 2) void k_attn(const unsigned short* __restrict__ Qh,
                                                 const unsigned short* __restrict__ Ql,
                                                 const unsigned short* __restrict__ Kh,
                                                 const unsigned short* __restrict__ Kl,
                                                 const unsigned short* __restrict__ Vt,
                                                 float* __restrict__ out) {
    __shared__ __attribute__((aligned(16))) unsigned short sKbuf[2 * 128 * 64]; // Kh|Kl, reused as P
    __shared__ __attribute__((aligned(16))) unsigned short sVT[64 * 128];
    char* const sKhB = (char*)sKbuf;            // 16 KB
    char* const sKlB = (char*)sKbuf + 16384;    // 16 KB
    int tid = threadIdx.x, lane = tid & 63, w = tid >> 6;
    int l15 = lane & 15, l4 = lane >> 4;
    char* const sPB = (char*)sKbuf + w * 8192;  // wave-private 8 KB P buffer [32 f][128 t]
    int qt = gridDim.x - 1 - blockIdx.x;        // heavy blocks first
    int bh = blockIdx.y;
    int b = bh >> 4, h = bh & 15;
    size_t head_off = (size_t)bh * S_ * CH;
    const unsigned short* Qhp = Qh + head_off;
    const unsigned short* Qlp = Ql + head_off;
    const unsigned short* Khp = Kh + head_off;
    const unsigned short* Klp = Kl + head_off;
    const unsigned short* Vtp = Vt + (size_t)bh * CH * S_;

    // Q fragments (pre-scaled by 1/8, hi/lo split); [nf][cc], B-operand rows = l15
    u16x8 qh[2][2], ql[2][2];
#pragma unroll
    for (int nf = 0; nf < 2; nf++)
#pragma unroll
        for (int cc = 0; cc < 2; cc++) {
            size_t o = (size_t)(qt * 128 + w * 32 + nf * 16 + l15) * CH + cc * 32 + l4 * 8;
            qh[nf][cc] = *(const u16x8*)(Qhp + o);
            ql[nf][cc] = *(const u16x8*)(Qlp + o);
        }

    f32x4 ctx[4][2] = {};                       // ctx^T: [c sub-tile][f sub-tile]
    float mrun[2] = {-1e30f, -1e30f}, lrun[2] = {0.f, 0.f};

    for (int kt = 0; kt <= qt; kt++) {
        __syncthreads();   // prev iteration's PV reads done; safe to overwrite K/P and V
        // stage K hi/lo: coalesced u16x8, XOR-swizzled LDS rows (128B, swz=(r&7)<<4)
#pragma unroll
        for (int j = 0; j < 4; j++) {
            int idx = tid + j * 256;           // 16B slot index
            int rr = idx >> 3, slot = idx & 7;
            size_t g = (size_t)(kt * 128 + rr) * CH + slot * 8;
            int bo = (slot * 16) ^ ((rr & 7) << 4);
            *(u16x8*)(sKhB + rr * 128 + bo) = *(const u16x8*)(Khp + g);
            *(u16x8*)(sKlB + rr * 128 + bo) = *(const u16x8*)(Klp + g);
        }
        // stage V^T rows (256B), swz=(c&15)<<4
#pragma unroll
        for (int j = 0; j < 4; j++) {
            int idx = tid + j * 256;
            int cc = idx >> 4, slot = idx & 15;
            size_t g = (size_t)cc * S_ + kt * 128 + slot * 8;
            int bo = (slot * 16) ^ ((cc & 15) << 4);
            *(u16x8*)((char*)sVT + cc * 256 + bo) = *(const u16x8*)(Vtp + g);
        }
        __syncthreads();

        // swapped scores: sa[mt][nf] = K-rows(t) x Q-rows(f), 3-term hi/lo bf16
        f32x4 sa[8][2];
#pragma unroll
        for (int mt = 0; mt < 8; mt++)
#pragma unroll
            for (int nf = 0; nf < 2; nf++) sa[mt][nf] = f32x4{0.f, 0.f, 0.f, 0.f};
        __builtin_amdgcn_s_setprio(1);
#pragma unroll
        for (int mt = 0; mt < 8; mt++) {
            int row = mt * 16 + l15;           // K row (A-operand M-row <-> l15)
            int sw = (row & 7) << 4;
            u16x8 kbh[2], kbl[2];
#pragma unroll
            for (int cc = 0; cc < 2; cc++) {
                int off = (cc * 64 + l4 * 16) ^ sw;
                kbh[cc] = *(const u16x8*)(sKhB + row * 128 + off);
                kbl[cc] = *(const u16x8*)(sKlB + row * 128 + off);
            }
#pragma unroll
            for (int nf = 0; nf < 2; nf++)
#pragma unroll
                for (int cc = 0; cc < 2; cc++) {
                    sa[mt][nf] = mfma16(kbh[cc], qh[nf][cc], sa[mt][nf]);
                    sa[mt][nf] = mfma16(kbl[cc], qh[nf][cc], sa[mt][nf]);
                    sa[mt][nf] = mfma16(kbh[cc], ql[nf][cc], sa[mt][nf]);
                }
        }
        __builtin_amdgcn_s_setprio(0);
        if (kt == qt) {  // causal mask inside diagonal tile: t > f
#pragma unroll
            for (int mt = 0; mt < 8; mt++)
#pragma unroll
                for (int nf = 0; nf < 2; nf++) {
                    int fq = w * 32 + nf * 16 + l15;
#pragma unroll
                    for (int jj = 0; jj < 4; jj++) {
                        int t = mt * 16 + l4 * 4 + jj;
                        if (t > fq) sa[mt][nf][jj] = -10000.0f;
                    }
                }
        }
        __syncthreads();   // all waves done reading K; K region becomes P region

        // in-register online softmax: lane owns Q-rows fl = nf*16+l15 (t split across l4)
#pragma unroll
        for (int nf = 0; nf < 2; nf++) {
            float pm = sa[0][nf][0];
#pragma unroll
            for (int mt = 0; mt < 8; mt++)
#pragma unroll
                for (int jj = 0; jj < 4; jj++) pm = fmaxf(pm, sa[mt][nf][jj]);
            pm = fmaxf(pm, __shfl_xor(pm, 16));
            pm = fmaxf(pm, __shfl_xor(pm, 32));
            float mnew = fmaxf(mrun[nf], pm);
            float sc = __expf(mrun[nf] - mnew);
            mrun[nf] = mnew;
            int fl = nf * 16 + l15;
            int swp = (fl & 15) << 4;
            float ps = 0.f;
#pragma unroll
            for (int mt = 0; mt < 8; mt++) {
                u16x4 pv4;
#pragma unroll
                for (int jj = 0; jj < 4; jj++) {
                    float p = __expf(sa[mt][nf][jj] - mnew);
                    ps += p;
                    pv4[jj] = f2bf(p);
                }
                *(u16x4*)(sPB + fl * 256 + ((mt * 32 + l4 * 8) ^ swp)) = pv4;
            }
            ps += __shfl_xor(ps, 16);
            ps += __shfl_xor(ps, 32);
            lrun[nf] = lrun[nf] * sc + ps;
#pragma unroll
            for (int mc = 0; mc < 4; mc++) ctx[mc][nf] *= sc;
        }

        // PV swapped: ctx^T += V^T x P  (A = sVT rows c, B = P rows f)
        __builtin_amdgcn_s_setprio(1);
#pragma unroll
        for (int tk = 0; tk < 4; tk++) {
            u16x8 pb[2];
#pragma unroll
            for (int nf = 0; nf < 2; nf++) {
                int fl = nf * 16 + l15;
                int off = (tk * 64 + l4 * 16) ^ ((fl & 15) << 4);
                pb[nf] = *(const u16x8*)(sPB + fl * 256 + off);
            }
#pragma unroll
            for (int mc = 0; mc < 4; mc++) {
                int rowv = mc * 16 + l15;
                int off = (tk * 64 + l4 * 16) ^ ((rowv & 15) << 4);
                u16x8 vb = *(const u16x8*)((char*)sVT + rowv * 256 + off);
#pragma unroll
                for (int nf = 0; nf < 2; nf++) ctx[mc][nf] = mfma16(vb, pb[nf], ctx[mc][nf]);
            }
        }
        __builtin_amdgcn_s_setprio(0);
    }
    // finalize: lrun is lane-local & complete; vectorized f32x4 stores
#pragma unroll
    for (int nf = 0; nf < 2; nf++) {
        float inv = 1.0f / lrun[nf];
        int fg = qt * 128 + w * 32 + nf * 16 + l15;
        float* op = out + ((size_t)(b * S_ + fg)) * HID + h * CH + l4 * 4;
#pragma unroll
        for (int mc = 0; mc < 4; mc++) {
            f32x4 o = ctx[mc][nf];
            o[0] *= inv; o[1] *= inv; o[2] *= inv; o[3] *= inv;
            *(f32x4*)(op + mc * 16) = o;
        }
    }
}

extern "C" void kernel_launch(void* const* d_in, const int* in_sizes, int n_in,
                              void* d_out, int out_size, void* d_ws, size_t ws_size,
                              hipStream_t stream) {
    const float* enc  = (const float*)d_in[0];
    const float* W    = (const float*)d_in[1];
    const float* bias = (const float*)d_in[2];
    float* out = (float*)d_out;

    unsigned short* A_hi = (unsigned short*)d_ws;
    unsigned short* A_lo = A_hi + (size_t)M_ * HID;
    unsigned short* WTh  = A_lo + (size_t)M_ * HID;
    unsigned short* WTl  = WTh + (size_t)N3 * HID;
    unsigned short* Qh   = WTl + (size_t)N3 * HID;
    unsigned short* Ql   = Qh + (size_t)M_ * HID;
    unsigned short* Kh   = Ql + (size_t)M_ * HID;
    unsigned short* Kl   = Kh + (size_t)M_ * HID;
    unsigned short* Vt   = Kl + (size_t)M_ * HID;

    int n8 = (M_ * HID) / 8;
    k_split<<<dim3(n8 / 256), 256, 0, stream>>>(enc, A_hi, A_lo, n8);
    k_tsplit<<<dim3(N3 / 32, HID / 32), 256, 0, stream>>>(W, WTh, WTl);
    k_gemm<<<dim3(N3 / 128, M_ / 128), 256, 0, stream>>>(A_hi, A_lo, WTh, WTl, bias,
                                                         Qh, Ql, Kh, Kl, Vt);
    k_attn<<<dim3(S_ / 128, B_ * NH), 256, 0, stream>>>(Qh, Ql, Kh, Kl, Vt, out);
}